// Round 4
// baseline (260.712 us; speedup 1.0000x reference)
//
#include <hip/hip_runtime.h>
#include <math.h>

#define DT   0.1f
#define HDT  0.005f
#define T_HIST 20
#define LEN_PRED 30
#define NLOG2E   (-1.4426950408889634f)
#define TWOLOG2E ( 2.8853900817779268f)

typedef __attribute__((ext_vector_type(8))) short bfrag8;   // 8 bf16 = 4 VGPRs
typedef __attribute__((ext_vector_type(4))) short short4v;  // 8 bytes
typedef __attribute__((ext_vector_type(4))) float f32x4;

// d_ws layout (bytes)
#define WS_FRAG   0u        // 96 frags * 512 bf16 * 2B = 98304
#define WS_WIN    98304u    // 2 frags * 1024B
#define WS_WOUT   100352u   // 1 frag * 1024B
#define WS_BIAS   101376u   // [2][3][32 feat][4 gate] f32 = 3072B (scaled, bih+bhh)

static __device__ __forceinline__ unsigned short f2bf(float x) {
    union { float f; unsigned int u; } v; v.f = x;
    unsigned int r = v.u + 0x7fffu + ((v.u >> 16) & 1u);   // RNE
    return (unsigned short)(r >> 16);
}

// sigmoid with pre-scaled (-log2e) input; tanh uses fma(-2, rcp1(z), 1) with +2log2e scale
static __device__ __forceinline__ float rcp1(float z) {
    return __builtin_amdgcn_rcpf(1.f + __builtin_amdgcn_exp2f(z));
}

// ---------------- weight prep: row-permuted MFMA A-frag order + exp2 pre-scale ----------------
// Layer frag (ph,l,wv,j,c): tile-row p maps to W row (p&3)*32 + wv*8 + 4*j + (p>>2)
// => D reg r = gate r, lane q = feat offset. Rows scaled: i/f/o by -log2e, g by 2log2e.
__global__ void prep_kernel(const float* __restrict__ Win_W,
                            const float* __restrict__ eWih, const float* __restrict__ eWhh,
                            const float* __restrict__ ebih, const float* __restrict__ ebhh,
                            const float* __restrict__ dWih, const float* __restrict__ dWhh,
                            const float* __restrict__ dbih, const float* __restrict__ dbhh,
                            const float* __restrict__ Wout_W,
                            char* __restrict__ ws)
{
    int i = blockIdx.x * blockDim.x + threadIdx.x;
    if (i < 49152) {
        int fi = i >> 9, within = i & 511;
        int lane = within >> 3, jj = within & 7;
        int c = fi & 1, j = (fi >> 1) & 1, wvv = (fi >> 2) & 3;
        int pl = fi >> 4;                 // ph*3 + l
        int l = pl % 3, ph = pl / 3;
        int m = lane & 15, q2 = lane >> 4;
        int gate = m & 3;
        int feat = wvv * 8 + 4 * j + (m >> 2);
        int row = gate * 32 + feat;
        int k = q2 * 8 + jj;
        float scale = (gate == 2) ? TWOLOG2E : NLOG2E;
        const float* W = (c == 0) ? (ph ? dWih : eWih) : (ph ? dWhh : eWhh);
        ((unsigned short*)(ws + WS_FRAG))[i] = f2bf(W[l * 4096 + row * 32 + k] * scale);
    } else if (i < 50176) {
        int i2 = i - 49152;
        int w = i2 >> 9, within = i2 & 511;
        int lane = within >> 3, jj = within & 7;
        int m = lane & 15, q2 = lane >> 4;
        int k = q2 * 8 + jj;
        float v = (k < 24) ? Win_W[(w * 16 + m) * 24 + k] * TWOLOG2E : 0.f;
        ((unsigned short*)(ws + WS_WIN))[i2] = f2bf(v);
    } else if (i < 50688) {
        int i3 = i - 50176;
        int lane = i3 >> 3, jj = i3 & 7;
        int m = lane & 15, q2 = lane >> 4;
        float v = (m < 4) ? Wout_W[m * 32 + q2 * 8 + jj] : 0.f;   // unscaled
        ((unsigned short*)(ws + WS_WOUT))[i3] = f2bf(v);
    } else if (i < 51456) {
        int b = i - 50688;                 // [ph][l][feat][gate], scaled combined bias
        int ph = b / 384, rem = b % 384;
        int l = rem >> 7, fg = rem & 127;
        int feat = fg >> 2, gate = fg & 3;
        int row = gate * 32 + feat;
        float scale = (gate == 2) ? TWOLOG2E : NLOG2E;
        const float* bi = ph ? dbih : ebih;
        const float* bh = ph ? dbhh : ebhh;
        ((float*)(ws + WS_BIAS))[b] = (bi[l * 128 + row] + bh[l * 128 + row]) * scale;
    }
}

// ---------------- main kernel: 16 elems / 8-wave block, 1 c-update per lane ----------------
// waves 0-3: layer MFMAs (gate-permuted tiles) -> fp32 pre-acts to LDS (D-contiguous)
// waves 6,7: Kalman x/y + Win + Wout
// all 8 waves: elementwise LSTM, lane owns output o = wv*64+lane = feat*16+elem
__launch_bounds__(512, 2)
__global__ void kalman_lstm_kernel(const float* __restrict__ hist,
                                   const float* __restrict__ max_ax, const float* __restrict__ max_ay,
                                   const float* __restrict__ vstd, const float* __restrict__ astd,
                                   const float* __restrict__ Rx_, const float* __restrict__ Ry_,
                                   const float* __restrict__ Gx, const float* __restrict__ Gy,
                                   const float* __restrict__ Win_b, const float* __restrict__ Wout_b,
                                   const char* __restrict__ ws, float* __restrict__ out)
{
    __shared__ __align__(16) unsigned short xin[4][16][40];     // layer inputs (x0, c0, c1, c2)
    __shared__ __align__(16) unsigned short hbuf[2][3][16][40]; // double-buffered h
    __shared__ __align__(16) unsigned short xpw[2][16][40];     // private XP per Kalman wave
    __shared__ __align__(16) float bias_lds[2][3][32][4];       // [ph][l][feat][gate] scaled
    __shared__ __align__(16) float pre[512][4];                 // fp32 pre-acts, o-major

    const int tid  = threadIdx.x;
    const int wv   = tid >> 6;        // 0..7
    const int lane = tid & 63;
    const int q    = lane >> 4;
    const int m    = lane & 15;       // elem index
    const int b_elem = blockIdx.x * 16 + m;

    // ---- MFMA waves: per-phase layer weights in registers (12 frags = 48 VGPRs) ----
    bfrag8 fragA[3][2][2];
    const bfrag8* fragp = (const bfrag8*)(ws + WS_FRAG);
    auto load_phase = [&](int ph) {
#pragma unroll
        for (int l = 0; l < 3; ++l)
#pragma unroll
            for (int j = 0; j < 2; ++j)
#pragma unroll
                for (int c = 0; c < 2; ++c) {
                    int fi = (((ph * 3 + l) * 4 + wv) * 2 + j) * 2 + c;
                    fragA[l][j][c] = fragp[fi * 64 + lane];
                }
    };
    if (wv < 4) load_phase(0);

    // ---- Kalman-wave state (waves 6,7; each lane: channel ch = q&1) ----
    bfrag8 winF = {}, woutF = {};
    f32x4 winB = {0.f, 0.f, 0.f, 0.f};
    float wb0 = 0.f, wb1 = 0.f, wb2 = 0.f, wb3 = 0.f;
    float g0 = 0.f, g1 = 0.f, g2 = 0.f, ge0 = 0.f, ge1 = 0.f, ge2 = 0.f;
    float Rch = 0.f, X0 = 0.f, X1 = 0.f, X2 = 0.f;
    float P00 = 0.f, P01 = 0.f, P02 = 0.f, P11 = 0.f, P12 = 0.f, P22 = 0.f;
    const int ch = q & 1;
    if (wv >= 6) {
        int w = wv - 6;
        winF  = ((const bfrag8*)(ws + WS_WIN))[w * 64 + lane];
        woutF = ((const bfrag8*)(ws + WS_WOUT))[lane];
#pragma unroll
        for (int r = 0; r < 4; ++r) winB[r] = Win_b[w * 16 + q * 4 + r] * TWOLOG2E;
        wb0 = Wout_b[0]; wb1 = Wout_b[1]; wb2 = Wout_b[2]; wb3 = Wout_b[3];
        const float rx = Rx_[0] * Rx_[0], ry = Ry_[0] * Ry_[0];
        Rch = ch ? ry : rx;
        if (ch == 0) { g0 = Gx[0]; g1 = Gx[1]; g2 = Gx[2]; float s = max_ax[0]; ge0 = g0*s; ge1 = g1*s; ge2 = g2*s; }
        else         { g0 = Gy[0]; g1 = Gy[1]; g2 = Gy[2]; float s = max_ay[0]; ge0 = g0*s; ge1 = g1*s; ge2 = g2*s; }
        X0 = hist[b_elem * (T_HIST * 2) + ch];
        P00 = Rch; P11 = vstd[0] * vstd[0]; P22 = astd[0] * astd[0];
    }

    float creg[3] = {0.f, 0.f, 0.f};

    // ---- LDS init ----
    for (int idx = tid; idx < 768; idx += 512)
        ((float*)bias_lds)[idx] = ((const float*)(ws + WS_BIAS))[idx];
    for (int idx = tid; idx < 4 * 16 * 40; idx += 512) (&xin[0][0][0])[idx] = 0;
    for (int idx = tid; idx < 2 * 3 * 16 * 40; idx += 512) (&hbuf[0][0][0][0])[idx] = 0;
    for (int idx = tid; idx < 2 * 16 * 40; idx += 512) (&xpw[0][0][0])[idx] = 0;

    auto kpred = [&](float Q00, float Q01, float Q02, float Q11, float Q12, float Q22) {
        X0 = X0 + DT * X1 + HDT * X2;
        X1 = X1 + DT * X2;
        float M00 = P00 + DT * P01 + HDT * P02;
        float M01 = P01 + DT * P11 + HDT * P12;
        float M02 = P02 + DT * P12 + HDT * P22;
        float M11 = P11 + DT * P12;
        float M12 = P12 + DT * P22;
        float M22 = P22;
        P00 = M00 + DT * M01 + HDT * M02 + Q00;
        P01 = M01 + DT * M02 + Q01;
        P02 = M02 + Q02;
        P11 = M11 + DT * M12 + Q11;
        P12 = M12 + Q12;
        P22 = M22 + Q22;
    };
    auto kupdate = [&](float z) {
        float y = z - X0;
        float Sinv = 1.0f / (P00 + Rch);
        float K0 = P00 * Sinv, K1 = P01 * Sinv, K2 = P02 * Sinv;
        X0 += y * K0; X1 += y * K1; X2 += y * K2;
        float p00 = P00, p01 = P01, p02 = P02;
        P00 = p00 - K0 * p00;
        P01 = p01 - K0 * p01;
        P02 = p02 - K0 * p02;
        P11 = P11 - K1 * p01;
        P12 = P12 - K1 * p02;
        P22 = P22 - K2 * p02;
    };
    auto write_xp = [&](int w) {      // q0 lanes: x-cols, q1 lanes: y-cols (private copy)
        if (q < 2) {
            unsigned short* row = &xpw[w][m][0];
            int o = ch * 3;
            row[o + 0] = f2bf(X0); row[o + 1] = f2bf(X1); row[o + 2] = f2bf(X2);
            int pb = 6 + ch * 9;
            row[pb + 0] = f2bf(P00); row[pb + 1] = f2bf(P01); row[pb + 2] = f2bf(P02);
            row[pb + 3] = f2bf(P01); row[pb + 4] = f2bf(P11); row[pb + 5] = f2bf(P12);
            row[pb + 6] = f2bf(P02); row[pb + 7] = f2bf(P12); row[pb + 8] = f2bf(P22);
        }
    };

    const f32x4 zero4 = {0.f, 0.f, 0.f, 0.f};

    // region A: waves 6,7 advance Kalman, write private XP, Win MFMA -> xin[0]
    auto regionA = [&](int mode, int t) {
        if (wv >= 6) {
            int w = wv - 6;
            if (mode == 0) {
                if (t > 0) {
                    float z = hist[b_elem * (T_HIST * 2) + t * 2 + ch];
                    kpred(ge0 * ge0, ge0 * ge1, ge0 * ge2, ge1 * ge1, ge1 * ge2, ge2 * ge2);
                    kupdate(z);
                }
            } else {
                if (t == 0) {      // finish encoder step 18 with z_19
                    float z = hist[b_elem * (T_HIST * 2) + 19 * 2 + ch];
                    kpred(ge0 * ge0, ge0 * ge1, ge0 * ge2, ge1 * ge1, ge1 * ge2, ge2 * ge2);
                    kupdate(z);
                } else {           // decoder step t-1: pred from c2, out store
                    bfrag8 bc2 = *(const bfrag8*)&xin[3][m][q * 8];
                    f32x4 ap = __builtin_amdgcn_mfma_f32_16x16x32_bf16(woutF, bc2, zero4, 0, 0, 0);
                    float a0 = ap[0] + wb0, a1 = ap[1] + wb1, a2 = ap[2] + wb2, a3 = ap[3] + wb3;
                    float s0 = __shfl(a0, m), s1 = __shfl(a1, m);
                    float s2 = __shfl(a2, m), s3 = __shfl(a3, m);
                    float pe = ch ? s1 : s0;
                    float qe = ch ? s3 : s2;
                    X2 = DT * pe;
                    float qs = qe * qe;
                    kpred(qs*g0*g0, qs*g0*g1, qs*g0*g2, qs*g1*g1, qs*g1*g2, qs*g2*g2);
                    if (wv == 6 && q < 2) {
                        float* o = out + (size_t)b_elem * (LEN_PRED * 5) + (t - 1) * 5;
                        if (ch == 0) { o[0] = X0; o[2] = sqrtf(P00); }
                        else         { o[1] = X0; o[3] = sqrtf(P00); o[4] = 0.f; }
                    }
                }
            }
            write_xp(w);
            // Win: x0 = tanh-scaled MFMA, bias in C operand
            bfrag8 bxp = *(const bfrag8*)&xpw[w][m][q * 8];
            f32x4 aw = __builtin_amdgcn_mfma_f32_16x16x32_bf16(winF, bxp, winB, 0, 0, 0);
            union { short4v v; unsigned short s[4]; } u;
#pragma unroll
            for (int r = 0; r < 4; ++r) u.s[r] = f2bf(fmaf(-2.f, rcp1(aw[r]), 1.f));
            *(short4v*)&xin[0][m][w * 16 + q * 4] = u.v;
        }
        __syncthreads();
    };

    auto layers = [&](int ph, int p) {
#pragma unroll
        for (int l = 0; l < 3; ++l) {
            if (wv < 4) {
                bfrag8 bx = *(const bfrag8*)&xin[l][m][q * 8];
                bfrag8 bh = *(const bfrag8*)&hbuf[p][l][m][q * 8];
                f32x4 b0 = *(const f32x4*)&bias_lds[ph][l][wv * 8 + q][0];       // broadcast read
                f32x4 b1 = *(const f32x4*)&bias_lds[ph][l][wv * 8 + 4 + q][0];
                f32x4 t0 = __builtin_amdgcn_mfma_f32_16x16x32_bf16(fragA[l][0][0], bx, b0, 0, 0, 0);
                f32x4 a0 = __builtin_amdgcn_mfma_f32_16x16x32_bf16(fragA[l][0][1], bh, t0, 0, 0, 0);
                f32x4 t1 = __builtin_amdgcn_mfma_f32_16x16x32_bf16(fragA[l][1][0], bx, b1, 0, 0, 0);
                f32x4 a1 = __builtin_amdgcn_mfma_f32_16x16x32_bf16(fragA[l][1][1], bh, t1, 0, 0, 0);
                *(f32x4*)&pre[(wv * 8 + q) * 16 + m][0] = a0;       // D-contiguous b128
                *(f32x4*)&pre[(wv * 8 + 4 + q) * 16 + m][0] = a1;
            }
            __syncthreads();
            // elementwise: 1 output per lane; pre-acts pre-scaled for exp2
            f32x4 g = *(const f32x4*)&pre[wv * 64 + lane][0];
            float iv = rcp1(g[0]);
            float fv = rcp1(g[1]);
            float gv = fmaf(-2.f, rcp1(g[2]), 1.f);
            float ov = rcp1(g[3]);
            float cn = fmaf(fv, creg[l], iv * gv);
            float tc = fmaf(-2.f, rcp1(cn * TWOLOG2E), 1.f);
            float hn = ov * tc;
            creg[l] = cn;
            int f = (wv << 2) + q;
            xin[l + 1][m][f] = f2bf(cn);
            hbuf[p ^ 1][l][m][f] = f2bf(hn);
            __syncthreads();
        }
    };

    __syncthreads();     // LDS init visible
    int p = 0;

    for (int t = 0; t < T_HIST - 1; ++t) { regionA(0, t); layers(0, p); p ^= 1; }
    if (wv < 4) load_phase(1);
    for (int t = 0; t < LEN_PRED; ++t)   { regionA(1, t); layers(1, p); p ^= 1; }

    // epilogue: decoder step 29's pred + out
    if (wv == 6) {
        bfrag8 bc2 = *(const bfrag8*)&xin[3][m][q * 8];
        f32x4 ap = __builtin_amdgcn_mfma_f32_16x16x32_bf16(woutF, bc2, zero4, 0, 0, 0);
        float a0 = ap[0] + wb0, a1 = ap[1] + wb1, a2 = ap[2] + wb2, a3 = ap[3] + wb3;
        float s0 = __shfl(a0, m), s1 = __shfl(a1, m);
        float s2 = __shfl(a2, m), s3 = __shfl(a3, m);
        float pe = ch ? s1 : s0;
        float qe = ch ? s3 : s2;
        X2 = DT * pe;
        float qs = qe * qe;
        kpred(qs*g0*g0, qs*g0*g1, qs*g0*g2, qs*g1*g1, qs*g1*g2, qs*g2*g2);
        if (q < 2) {
            float* o = out + (size_t)b_elem * (LEN_PRED * 5) + (LEN_PRED - 1) * 5;
            if (ch == 0) { o[0] = X0; o[2] = sqrtf(P00); }
            else         { o[1] = X0; o[3] = sqrtf(P00); o[4] = 0.f; }
        }
    }
}

extern "C" void kernel_launch(void* const* d_in, const int* in_sizes, int n_in,
                              void* d_out, int out_size, void* d_ws, size_t ws_size,
                              hipStream_t stream)
{
    const float* hist  = (const float*)d_in[0];
    const float* maxax = (const float*)d_in[1];
    const float* maxay = (const float*)d_in[2];
    const float* vstd  = (const float*)d_in[3];
    const float* astd  = (const float*)d_in[4];
    const float* Rx    = (const float*)d_in[5];
    const float* Ry    = (const float*)d_in[6];
    const float* Gx    = (const float*)d_in[7];
    const float* Gy    = (const float*)d_in[8];
    const float* WinW  = (const float*)d_in[9];
    const float* Winb  = (const float*)d_in[10];
    const float* eWih  = (const float*)d_in[11];
    const float* eWhh  = (const float*)d_in[12];
    const float* ebih  = (const float*)d_in[13];
    const float* ebhh  = (const float*)d_in[14];
    const float* dWih  = (const float*)d_in[15];
    const float* dWhh  = (const float*)d_in[16];
    const float* dbih  = (const float*)d_in[17];
    const float* dbhh  = (const float*)d_in[18];
    const float* WoutW = (const float*)d_in[19];
    const float* Woutb = (const float*)d_in[20];
    char* ws = (char*)d_ws;
    float* out = (float*)d_out;

    prep_kernel<<<202, 256, 0, stream>>>(WinW, eWih, eWhh, ebih, ebhh,
                                         dWih, dWhh, dbih, dbhh, WoutW, ws);
    kalman_lstm_kernel<<<512, 512, 0, stream>>>(hist, maxax, maxay, vstd, astd,
                                                Rx, Ry, Gx, Gy, Winb, Woutb,
                                                ws, out);
}

// Round 5
// 234.145 us; speedup vs baseline: 1.1135x; 1.1135x over previous
//
#include <hip/hip_runtime.h>
#include <math.h>

#define DT   0.1f
#define HDT  0.005f
#define T_HIST 20
#define LEN_PRED 30
#define NLOG2E   (-1.4426950408889634f)
#define TWOLOG2E ( 2.8853900817779268f)

typedef __attribute__((ext_vector_type(8))) short bfrag8;   // 8 bf16 = 4 VGPRs
typedef __attribute__((ext_vector_type(4))) short short4v;  // 8 bytes
typedef __attribute__((ext_vector_type(4))) float f32x4;

// d_ws layout (bytes)
#define WS_FRAG   0u        // 96 frags * 512 bf16 * 2B = 98304
#define WS_WIN    98304u    // 2 frags * 1024B
#define WS_WOUT   100352u   // 1 frag * 1024B
#define WS_BIAS   101376u   // [2][3][32 feat][4 gate] f32 = 3072B (scaled, bih+bhh)

static __device__ __forceinline__ unsigned short f2bf(float x) {
    union { float f; unsigned int u; } v; v.f = x;
    unsigned int r = v.u + 0x7fffu + ((v.u >> 16) & 1u);   // RNE
    return (unsigned short)(r >> 16);
}

// sigmoid with pre-scaled (-log2e) input; tanh = 1-2*rcp1 with +2log2e scale
static __device__ __forceinline__ float rcp1(float z) {
    return __builtin_amdgcn_rcpf(1.f + __builtin_amdgcn_exp2f(z));
}

// ---------------- weight prep: row-permuted MFMA A-frag order + exp2 pre-scale ----------------
// Layer frag (ph,l,wv,j,c): tile-row p maps to W row (p&3)*32 + wv*8 + 4*j + (p>>2)
// => D reg r = gate r, lane q = feat offset, col m = elem. i/f/o rows * -log2e, g rows * 2log2e.
__global__ void prep_kernel(const float* __restrict__ Win_W,
                            const float* __restrict__ eWih, const float* __restrict__ eWhh,
                            const float* __restrict__ ebih, const float* __restrict__ ebhh,
                            const float* __restrict__ dWih, const float* __restrict__ dWhh,
                            const float* __restrict__ dbih, const float* __restrict__ dbhh,
                            const float* __restrict__ Wout_W,
                            char* __restrict__ ws)
{
    int i = blockIdx.x * blockDim.x + threadIdx.x;
    if (i < 49152) {
        int fi = i >> 9, within = i & 511;
        int lane = within >> 3, jj = within & 7;
        int c = fi & 1, j = (fi >> 1) & 1, wvv = (fi >> 2) & 3;
        int pl = fi >> 4;                 // ph*3 + l
        int l = pl % 3, ph = pl / 3;
        int m = lane & 15, q2 = lane >> 4;
        int gate = m & 3;
        int feat = wvv * 8 + 4 * j + (m >> 2);
        int row = gate * 32 + feat;
        int k = q2 * 8 + jj;
        float scale = (gate == 2) ? TWOLOG2E : NLOG2E;
        const float* W = (c == 0) ? (ph ? dWih : eWih) : (ph ? dWhh : eWhh);
        ((unsigned short*)(ws + WS_FRAG))[i] = f2bf(W[l * 4096 + row * 32 + k] * scale);
    } else if (i < 50176) {
        int i2 = i - 49152;
        int w = i2 >> 9, within = i2 & 511;
        int lane = within >> 3, jj = within & 7;
        int m = lane & 15, q2 = lane >> 4;
        int k = q2 * 8 + jj;
        float v = (k < 24) ? Win_W[(w * 16 + m) * 24 + k] * TWOLOG2E : 0.f;
        ((unsigned short*)(ws + WS_WIN))[i2] = f2bf(v);
    } else if (i < 50688) {
        int i3 = i - 50176;
        int lane = i3 >> 3, jj = i3 & 7;
        int m = lane & 15, q2 = lane >> 4;
        float v = (m < 4) ? Wout_W[m * 32 + q2 * 8 + jj] : 0.f;   // unscaled
        ((unsigned short*)(ws + WS_WOUT))[i3] = f2bf(v);
    } else if (i < 51456) {
        int b = i - 50688;                 // [ph][l][feat][gate], scaled combined bias
        int ph = b / 384, rem = b % 384;
        int l = rem >> 7, fg = rem & 127;
        int feat = fg >> 2, gate = fg & 3;
        int row = gate * 32 + feat;
        float scale = (gate == 2) ? TWOLOG2E : NLOG2E;
        const float* bi = ph ? dbih : ebih;
        const float* bh = ph ? dbhh : ebhh;
        ((float*)(ws + WS_BIAS))[b] = (bi[l * 128 + row] + bh[l * 128 + row]) * scale;
    }
}

// ---------------- main kernel: 8 elems / 4-wave block, 1024 blocks (4/CU) ----------------
// All 4 waves: layer MFMA (feats wv*8..+7) -> ds_bpermute repack -> dense elementwise (1/lane).
// Waves 2,3: Kalman x+y (ch=q&1, redundant private copies) + Win; Wout in decoder.
__launch_bounds__(256, 4)
__global__ void kalman_lstm_kernel(const float* __restrict__ hist,
                                   const float* __restrict__ max_ax, const float* __restrict__ max_ay,
                                   const float* __restrict__ vstd, const float* __restrict__ astd,
                                   const float* __restrict__ Rx_, const float* __restrict__ Ry_,
                                   const float* __restrict__ Gx, const float* __restrict__ Gy,
                                   const float* __restrict__ Win_b, const float* __restrict__ Wout_b,
                                   const char* __restrict__ ws, float* __restrict__ out)
{
    __shared__ __align__(16) unsigned short xin[4][16][40];     // rows 8..15 stay zero
    __shared__ __align__(16) unsigned short hbuf[2][3][16][40]; // rows 8..15 stay zero
    __shared__ __align__(16) unsigned short xpw[2][16][40];     // private XP per Kalman wave
    __shared__ __align__(16) float bias_lds[2][3][32][4];       // [ph][l][feat][gate] scaled

    const int tid  = threadIdx.x;
    const int wv   = tid >> 6;        // 0..3
    const int lane = tid & 63;
    const int q    = lane >> 4;
    const int m    = lane & 15;       // MFMA col = elem (0..7 valid)
    const bool elv = (m < 8);
    const int b_elem = blockIdx.x * 8 + m;          // valid only when elv
    // repack ownership: lane owns output (feat wv*8+fw, elem e8)
    const int e8 = lane & 7;
    const int fw = lane >> 3;                       // 0..7
    const int srcb = (((fw & 3) << 4) + e8) << 2;   // source lane byte addr for bpermute

    // ---- per-phase layer weights in registers (12 frags = 48 VGPRs) ----
    bfrag8 fragA[3][2][2];
    const bfrag8* fragp = (const bfrag8*)(ws + WS_FRAG);
    auto load_phase = [&](int ph) {
#pragma unroll
        for (int l = 0; l < 3; ++l)
#pragma unroll
            for (int j = 0; j < 2; ++j)
#pragma unroll
                for (int c = 0; c < 2; ++c) {
                    int fi = (((ph * 3 + l) * 4 + wv) * 2 + j) * 2 + c;
                    fragA[l][j][c] = fragp[fi * 64 + lane];
                }
    };
    load_phase(0);

    // ---- Kalman-wave state (waves 2,3; lane channel ch = q&1) ----
    bfrag8 winF = {}, woutF = {};
    f32x4 winB = {0.f, 0.f, 0.f, 0.f};
    float wb0 = 0.f, wb1 = 0.f, wb2 = 0.f, wb3 = 0.f;
    float g0 = 0.f, g1 = 0.f, g2 = 0.f, ge0 = 0.f, ge1 = 0.f, ge2 = 0.f;
    float Rch = 0.f, X0 = 0.f, X1 = 0.f, X2 = 0.f;
    float P00 = 0.f, P01 = 0.f, P02 = 0.f, P11 = 0.f, P12 = 0.f, P22 = 0.f;
    const int ch = q & 1;
    if (wv >= 2) {
        int w = wv - 2;
        winF  = ((const bfrag8*)(ws + WS_WIN))[w * 64 + lane];
        woutF = ((const bfrag8*)(ws + WS_WOUT))[lane];
#pragma unroll
        for (int r = 0; r < 4; ++r) winB[r] = Win_b[w * 16 + q * 4 + r] * TWOLOG2E;
        wb0 = Wout_b[0]; wb1 = Wout_b[1]; wb2 = Wout_b[2]; wb3 = Wout_b[3];
        const float rx = Rx_[0] * Rx_[0], ry = Ry_[0] * Ry_[0];
        Rch = ch ? ry : rx;
        if (ch == 0) { g0 = Gx[0]; g1 = Gx[1]; g2 = Gx[2]; float s = max_ax[0]; ge0 = g0*s; ge1 = g1*s; ge2 = g2*s; }
        else         { g0 = Gy[0]; g1 = Gy[1]; g2 = Gy[2]; float s = max_ay[0]; ge0 = g0*s; ge1 = g1*s; ge2 = g2*s; }
        X0 = elv ? hist[b_elem * (T_HIST * 2) + ch] : 0.f;
        P00 = Rch; P11 = vstd[0] * vstd[0]; P22 = astd[0] * astd[0];
    }

    float creg[3] = {0.f, 0.f, 0.f};

    // ---- LDS init ----
    for (int idx = tid; idx < 768; idx += 256)
        ((float*)bias_lds)[idx] = ((const float*)(ws + WS_BIAS))[idx];
    for (int idx = tid; idx < 4 * 16 * 40; idx += 256) (&xin[0][0][0])[idx] = 0;
    for (int idx = tid; idx < 2 * 3 * 16 * 40; idx += 256) (&hbuf[0][0][0][0])[idx] = 0;
    for (int idx = tid; idx < 2 * 16 * 40; idx += 256) (&xpw[0][0][0])[idx] = 0;

    auto kpred = [&](float Q00, float Q01, float Q02, float Q11, float Q12, float Q22) {
        X0 = X0 + DT * X1 + HDT * X2;
        X1 = X1 + DT * X2;
        float M00 = P00 + DT * P01 + HDT * P02;
        float M01 = P01 + DT * P11 + HDT * P12;
        float M02 = P02 + DT * P12 + HDT * P22;
        float M11 = P11 + DT * P12;
        float M12 = P12 + DT * P22;
        float M22 = P22;
        P00 = M00 + DT * M01 + HDT * M02 + Q00;
        P01 = M01 + DT * M02 + Q01;
        P02 = M02 + Q02;
        P11 = M11 + DT * M12 + Q11;
        P12 = M12 + Q12;
        P22 = M22 + Q22;
    };
    auto kupdate = [&](float z) {
        float y = z - X0;
        float Sinv = 1.0f / (P00 + Rch);
        float K0 = P00 * Sinv, K1 = P01 * Sinv, K2 = P02 * Sinv;
        X0 += y * K0; X1 += y * K1; X2 += y * K2;
        float p00 = P00, p01 = P01, p02 = P02;
        P00 = p00 - K0 * p00;
        P01 = p01 - K0 * p01;
        P02 = p02 - K0 * p02;
        P11 = P11 - K1 * p01;
        P12 = P12 - K1 * p02;
        P22 = P22 - K2 * p02;
    };
    auto write_xp = [&](int w) {      // q0: x-cols, q1: y-cols; elems 0..7 only
        if (q < 2 && elv) {
            unsigned short* row = &xpw[w][m][0];
            int o = ch * 3;
            row[o + 0] = f2bf(X0); row[o + 1] = f2bf(X1); row[o + 2] = f2bf(X2);
            int pb = 6 + ch * 9;
            row[pb + 0] = f2bf(P00); row[pb + 1] = f2bf(P01); row[pb + 2] = f2bf(P02);
            row[pb + 3] = f2bf(P01); row[pb + 4] = f2bf(P11); row[pb + 5] = f2bf(P12);
            row[pb + 6] = f2bf(P02); row[pb + 7] = f2bf(P12); row[pb + 8] = f2bf(P22);
        }
    };

    const f32x4 zero4 = {0.f, 0.f, 0.f, 0.f};

    // region A: waves 2,3 advance Kalman, write private XP, Win MFMA -> xin[0]
    auto regionA = [&](int mode, int t) {
        if (wv >= 2) {
            int w = wv - 2;
            if (mode == 0) {
                if (t > 0) {
                    float z = elv ? hist[b_elem * (T_HIST * 2) + t * 2 + ch] : 0.f;
                    kpred(ge0 * ge0, ge0 * ge1, ge0 * ge2, ge1 * ge1, ge1 * ge2, ge2 * ge2);
                    kupdate(z);
                }
            } else {
                if (t == 0) {      // finish encoder step 18 with z_19
                    float z = elv ? hist[b_elem * (T_HIST * 2) + 19 * 2 + ch] : 0.f;
                    kpred(ge0 * ge0, ge0 * ge1, ge0 * ge2, ge1 * ge1, ge1 * ge2, ge2 * ge2);
                    kupdate(z);
                } else {           // decoder step t-1: pred from c2, out store
                    bfrag8 bc2 = *(const bfrag8*)&xin[3][m][q * 8];
                    f32x4 ap = __builtin_amdgcn_mfma_f32_16x16x32_bf16(woutF, bc2, zero4, 0, 0, 0);
                    float a0 = ap[0] + wb0, a1 = ap[1] + wb1, a2 = ap[2] + wb2, a3 = ap[3] + wb3;
                    float s0 = __shfl(a0, m), s1 = __shfl(a1, m);
                    float s2 = __shfl(a2, m), s3 = __shfl(a3, m);
                    float pe = ch ? s1 : s0;
                    float qe = ch ? s3 : s2;
                    X2 = DT * pe;
                    float qs = qe * qe;
                    kpred(qs*g0*g0, qs*g0*g1, qs*g0*g2, qs*g1*g1, qs*g1*g2, qs*g2*g2);
                    if (wv == 2 && q < 2 && elv) {
                        float* o = out + (size_t)b_elem * (LEN_PRED * 5) + (t - 1) * 5;
                        if (ch == 0) { o[0] = X0; o[2] = sqrtf(P00); }
                        else         { o[1] = X0; o[3] = sqrtf(P00); o[4] = 0.f; }
                    }
                }
            }
            write_xp(w);
            // Win: x0 = tanh-scaled MFMA, bias in C operand (cols 8..15 junk, discarded)
            bfrag8 bxp = *(const bfrag8*)&xpw[w][m][q * 8];
            f32x4 aw = __builtin_amdgcn_mfma_f32_16x16x32_bf16(winF, bxp, winB, 0, 0, 0);
            union { short4v v; unsigned short s[4]; } u;
#pragma unroll
            for (int r = 0; r < 4; ++r) u.s[r] = f2bf(fmaf(-2.f, rcp1(aw[r]), 1.f));
            *(short4v*)&xin[0][m][w * 16 + q * 4] = u.v;
        }
        __syncthreads();
    };

    auto layers = [&](int ph, int p) {
#pragma unroll
        for (int l = 0; l < 3; ++l) {
            // MFMA: wave wv -> feats wv*8..+7, elems = cols (0..7 valid)
            bfrag8 bx = *(const bfrag8*)&xin[l][m][q * 8];
            bfrag8 bh = *(const bfrag8*)&hbuf[p][l][m][q * 8];
            f32x4 b0 = *(const f32x4*)&bias_lds[ph][l][wv * 8 + q][0];       // broadcast
            f32x4 b1 = *(const f32x4*)&bias_lds[ph][l][wv * 8 + 4 + q][0];
            f32x4 t0 = __builtin_amdgcn_mfma_f32_16x16x32_bf16(fragA[l][0][0], bx, b0, 0, 0, 0);
            f32x4 a0 = __builtin_amdgcn_mfma_f32_16x16x32_bf16(fragA[l][0][1], bh, t0, 0, 0, 0);
            f32x4 t1 = __builtin_amdgcn_mfma_f32_16x16x32_bf16(fragA[l][1][0], bx, b1, 0, 0, 0);
            f32x4 a1 = __builtin_amdgcn_mfma_f32_16x16x32_bf16(fragA[l][1][1], bh, t1, 0, 0, 0);
            // in-register repack: lane -> (feat wv*8+fw, elem e8); src lane (fw&3)*16+e8
            float g[4];
#pragma unroll
            for (int r = 0; r < 4; ++r) {
                float p0 = __int_as_float(__builtin_amdgcn_ds_bpermute(srcb, __float_as_int(a0[r])));
                float p1 = __int_as_float(__builtin_amdgcn_ds_bpermute(srcb, __float_as_int(a1[r])));
                g[r] = (fw >= 4) ? p1 : p0;
            }
            // dense elementwise: 1 output per lane
            float iv = rcp1(g[0]);
            float fv = rcp1(g[1]);
            float gv = fmaf(-2.f, rcp1(g[2]), 1.f);
            float ov = rcp1(g[3]);
            float cn = fmaf(fv, creg[l], iv * gv);
            float tc = fmaf(-2.f, rcp1(cn * TWOLOG2E), 1.f);
            float hn = ov * tc;
            creg[l] = cn;
            int f = wv * 8 + fw;
            xin[l + 1][e8][f] = f2bf(cn);
            hbuf[p ^ 1][l][e8][f] = f2bf(hn);
            __syncthreads();
        }
    };

    __syncthreads();     // LDS init visible
    int p = 0;

    for (int t = 0; t < T_HIST - 1; ++t) { regionA(0, t); layers(0, p); p ^= 1; }
    load_phase(1);
    for (int t = 0; t < LEN_PRED; ++t)   { regionA(1, t); layers(1, p); p ^= 1; }

    // epilogue: decoder step 29's pred + out
    if (wv == 2) {
        bfrag8 bc2 = *(const bfrag8*)&xin[3][m][q * 8];
        f32x4 ap = __builtin_amdgcn_mfma_f32_16x16x32_bf16(woutF, bc2, zero4, 0, 0, 0);
        float a0 = ap[0] + wb0, a1 = ap[1] + wb1, a2 = ap[2] + wb2, a3 = ap[3] + wb3;
        float s0 = __shfl(a0, m), s1 = __shfl(a1, m);
        float s2 = __shfl(a2, m), s3 = __shfl(a3, m);
        float pe = ch ? s1 : s0;
        float qe = ch ? s3 : s2;
        X2 = DT * pe;
        float qs = qe * qe;
        kpred(qs*g0*g0, qs*g0*g1, qs*g0*g2, qs*g1*g1, qs*g1*g2, qs*g2*g2);
        if (q < 2 && elv) {
            float* o = out + (size_t)b_elem * (LEN_PRED * 5) + (LEN_PRED - 1) * 5;
            if (ch == 0) { o[0] = X0; o[2] = sqrtf(P00); }
            else         { o[1] = X0; o[3] = sqrtf(P00); o[4] = 0.f; }
        }
    }
}

extern "C" void kernel_launch(void* const* d_in, const int* in_sizes, int n_in,
                              void* d_out, int out_size, void* d_ws, size_t ws_size,
                              hipStream_t stream)
{
    const float* hist  = (const float*)d_in[0];
    const float* maxax = (const float*)d_in[1];
    const float* maxay = (const float*)d_in[2];
    const float* vstd  = (const float*)d_in[3];
    const float* astd  = (const float*)d_in[4];
    const float* Rx    = (const float*)d_in[5];
    const float* Ry    = (const float*)d_in[6];
    const float* Gx    = (const float*)d_in[7];
    const float* Gy    = (const float*)d_in[8];
    const float* WinW  = (const float*)d_in[9];
    const float* Winb  = (const float*)d_in[10];
    const float* eWih  = (const float*)d_in[11];
    const float* eWhh  = (const float*)d_in[12];
    const float* ebih  = (const float*)d_in[13];
    const float* ebhh  = (const float*)d_in[14];
    const float* dWih  = (const float*)d_in[15];
    const float* dWhh  = (const float*)d_in[16];
    const float* dbih  = (const float*)d_in[17];
    const float* dbhh  = (const float*)d_in[18];
    const float* WoutW = (const float*)d_in[19];
    const float* Woutb = (const float*)d_in[20];
    char* ws = (char*)d_ws;
    float* out = (float*)d_out;

    prep_kernel<<<202, 256, 0, stream>>>(WinW, eWih, eWhh, ebih, ebhh,
                                         dWih, dWhh, dbih, dbhh, WoutW, ws);
    kalman_lstm_kernel<<<1024, 256, 0, stream>>>(hist, maxax, maxay, vstd, astd,
                                                 Rx, Ry, Gx, Gy, Winb, Woutb,
                                                 ws, out);
}

// Round 6
// 217.121 us; speedup vs baseline: 1.2008x; 1.0784x over previous
//
#include <hip/hip_runtime.h>
#include <math.h>

#define DT   0.1f
#define HDT  0.005f
#define T_HIST 20
#define LEN_PRED 30
#define NLOG2E   (-1.4426950408889634f)
#define TWOLOG2E ( 2.8853900817779268f)

typedef __attribute__((ext_vector_type(8))) short bfrag8;   // 8 bf16 = 4 VGPRs
typedef __attribute__((ext_vector_type(4))) float f32x4;

// d_ws layout (bytes)
#define WS_FRAG  0u          // 96 frags * 512 bf16 * 2B = 98304
#define WS_WIN   98304u      // 2 frags * 1024B
#define WS_WOUT  100352u     // 1 frag * 1024B
#define WS_BIASC 101376u     // 96 f32x4 = 1536B  [(ph*3+l)*8+j][q] scaled bih+bhh
#define WS_WINC  102912u     // 8 f32x4 = 128B    [T][q] scaled Win_b
#define WS_WOUTB 103040u     // 4 floats

static __device__ __forceinline__ unsigned short f2bf(float x) {
    union { float f; unsigned int u; } v; v.f = x;
    unsigned int r = v.u + 0x7fffu + ((v.u >> 16) & 1u);   // RNE
    return (unsigned short)(r >> 16);
}

// pack two floats to bf16x2 (round-half-up): lo in low16, hi in high16
static __device__ __forceinline__ unsigned int pack2bf(float lo, float hi) {
    unsigned int ul = __float_as_uint(lo) + 0x8000u;
    unsigned int uh = __float_as_uint(hi) + 0x8000u;
    return __builtin_amdgcn_perm(uh, ul, 0x07060302u);   // {uh[31:16], ul[31:16]}
}

static __device__ __forceinline__ float rcp1(float z) {   // 1/(1+2^z)
    return __builtin_amdgcn_rcpf(1.f + __builtin_amdgcn_exp2f(z));
}
static __device__ __forceinline__ float th_(float z) {    // tanh-form, z pre-scaled 2log2e
    return fmaf(-2.f, rcp1(z), 1.f);
}

// ---------------- weight prep ----------------
// Layer tile j: row p ==> W-row (p&3)*32 + 8*(p>>2) + j  => D at lane(q,m): reg r = gate r,
// feat = 8q+j, elem = m  => elementwise output IS the next MFMA's B-fragment. Rows pre-scaled
// for exp2 (i/f/o: -log2e, g: 2log2e). Win tile T: row p ==> feat 8*(p>>2)+4T+(p&3).
__global__ void prep_kernel(const float* __restrict__ Win_W, const float* __restrict__ Win_b,
                            const float* __restrict__ eWih, const float* __restrict__ eWhh,
                            const float* __restrict__ ebih, const float* __restrict__ ebhh,
                            const float* __restrict__ dWih, const float* __restrict__ dWhh,
                            const float* __restrict__ dbih, const float* __restrict__ dbhh,
                            const float* __restrict__ Wout_W, const float* __restrict__ Wout_b,
                            char* __restrict__ ws)
{
    int i = blockIdx.x * blockDim.x + threadIdx.x;
    if (i < 49152) {
        int fi = i >> 9, w = i & 511;
        int lane = w >> 3, jj = w & 7;
        int c = fi & 1, j = (fi >> 1) & 7, pl = fi >> 4;
        int l = pl % 3, ph = pl / 3;
        int mm = lane & 15, qq = lane >> 4;
        int gate = mm & 3;
        int row = gate * 32 + 8 * (mm >> 2) + j;
        int k = qq * 8 + jj;
        float scale = (gate == 2) ? TWOLOG2E : NLOG2E;
        const float* W = c ? (ph ? dWhh : eWhh) : (ph ? dWih : eWih);
        ((unsigned short*)(ws + WS_FRAG))[i] = f2bf(W[l * 4096 + row * 32 + k] * scale);
    } else if (i < 50176) {
        int i2 = i - 49152;
        int T = i2 >> 9, w = i2 & 511;
        int lane = w >> 3, jj = w & 7;
        int mm = lane & 15, qq = lane >> 4;
        int feat = 8 * (mm >> 2) + 4 * T + (mm & 3);
        int k = qq * 8 + jj;
        float v = (k < 24) ? Win_W[feat * 24 + k] * TWOLOG2E : 0.f;
        ((unsigned short*)(ws + WS_WIN))[i2] = f2bf(v);
    } else if (i < 50688) {
        int i3 = i - 50176;
        int lane = i3 >> 3, jj = i3 & 7;
        int mm = lane & 15, qq = lane >> 4;
        float v = (mm < 4) ? Wout_W[mm * 32 + qq * 8 + jj] : 0.f;   // unscaled
        ((unsigned short*)(ws + WS_WOUT))[i3] = f2bf(v);
    } else if (i < 51072) {
        int b = i - 50688;                 // ((ph*3+l)*8+j)*16 + q*4 + r
        int r = b & 3, qq = (b >> 2) & 3, j = (b >> 4) & 7, pl = b >> 7;
        int l = pl % 3, ph = pl / 3;
        int row = r * 32 + 8 * qq + j;
        float scale = (r == 2) ? TWOLOG2E : NLOG2E;
        const float* bi = ph ? dbih : ebih;
        const float* bh = ph ? dbhh : ebhh;
        ((float*)(ws + WS_BIASC))[b] = (bi[l * 128 + row] + bh[l * 128 + row]) * scale;
    } else if (i < 51104) {
        int b = i - 51072;                 // T*16 + q*4 + r -> Win_b[8q+4T+r]
        int r = b & 3, qq = (b >> 2) & 3, T = b >> 4;
        ((float*)(ws + WS_WINC))[b] = Win_b[8 * qq + 4 * T + r] * TWOLOG2E;
    } else if (i < 51108) {
        ((float*)(ws + WS_WOUTB))[i - 51104] = Wout_b[i - 51104];
    }
}

// ---------------- main kernel: ONE wave owns 16 elems end-to-end, zero barriers ----------------
__launch_bounds__(64)
__global__ void kalman_lstm_kernel(const float* __restrict__ hist,
                                   const float* __restrict__ max_ax, const float* __restrict__ max_ay,
                                   const float* __restrict__ vstd, const float* __restrict__ astd,
                                   const float* __restrict__ Rx_, const float* __restrict__ Ry_,
                                   const float* __restrict__ Gx, const float* __restrict__ Gy,
                                   const char* __restrict__ ws, float* __restrict__ out)
{
    __shared__ unsigned short xp[16][40];   // wave-private XP staging (cols 24..39 stay 0)

    const int lane = threadIdx.x;
    const int q = lane >> 4, m = lane & 15, ch = q & 1;
    const int b_elem = blockIdx.x * 16 + m;

    for (int i = lane; i < 640; i += 64) (&xp[0][0])[i] = 0;
    __builtin_amdgcn_wave_barrier();

    // ---- full weight stack in registers (per phase) ----
    bfrag8 fragA[3][8][2];     // [layer][tile j][0=ih,1=hh]
    f32x4  biasC[3][8];        // MFMA C-operand biases
    const bfrag8* fragp = (const bfrag8*)(ws + WS_FRAG);
    const f32x4*  biasp = (const f32x4*)(ws + WS_BIASC);
    auto load_phase = [&](int ph) {
#pragma unroll
        for (int l = 0; l < 3; ++l)
#pragma unroll
            for (int j = 0; j < 8; ++j) {
#pragma unroll
                for (int c = 0; c < 2; ++c)
                    fragA[l][j][c] = fragp[(((ph * 3 + l) * 8 + j) * 2 + c) * 64 + lane];
                biasC[l][j] = biasp[((ph * 3 + l) * 8 + j) * 4 + q];
            }
    };
    load_phase(0);

    bfrag8 winF0 = ((const bfrag8*)(ws + WS_WIN))[lane];
    bfrag8 winF1 = ((const bfrag8*)(ws + WS_WIN))[64 + lane];
    f32x4  winC0 = ((const f32x4*)(ws + WS_WINC))[q];
    f32x4  winC1 = ((const f32x4*)(ws + WS_WINC))[4 + q];
    bfrag8 woutF = ((const bfrag8*)(ws + WS_WOUT))[lane];
    const float* wbp = (const float*)(ws + WS_WOUTB);
    const float wb0 = wbp[0], wb1 = wbp[1], wb2 = wbp[2], wb3 = wbp[3];

    // ---- Kalman state (q<2 lanes authoritative; others junk-but-finite) ----
    const float rx = Rx_[0] * Rx_[0], ry = Ry_[0] * Ry_[0];
    const float Rch = ch ? ry : rx;
    float g0, g1, g2, s;
    if (ch == 0) { g0 = Gx[0]; g1 = Gx[1]; g2 = Gx[2]; s = max_ax[0]; }
    else         { g0 = Gy[0]; g1 = Gy[1]; g2 = Gy[2]; s = max_ay[0]; }
    const float ge0 = g0 * s, ge1 = g1 * s, ge2 = g2 * s;
    float X0 = (q < 2) ? hist[b_elem * 40 + ch] : 0.f;
    float X1 = 0.f, X2 = 0.f;
    float P00 = Rch, P01 = 0.f, P02 = 0.f;
    float P11 = vstd[0] * vstd[0], P12 = 0.f, P22 = astd[0] * astd[0];

    // ---- LSTM state, fully register-resident ----
    union { unsigned int u[4]; bfrag8 v; } zf; zf.u[0] = zf.u[1] = zf.u[2] = zf.u[3] = 0;
    bfrag8 hfrag[3] = { zf.v, zf.v, zf.v };
    float cst[3][8];
#pragma unroll
    for (int l = 0; l < 3; ++l)
#pragma unroll
        for (int j = 0; j < 8; ++j) cst[l][j] = 0.f;
    bfrag8 xfrag = zf.v;

    auto kpred = [&](float Q00, float Q01, float Q02, float Q11, float Q12, float Q22) {
        X0 = X0 + DT * X1 + HDT * X2;
        X1 = X1 + DT * X2;
        float M00 = P00 + DT * P01 + HDT * P02;
        float M01 = P01 + DT * P11 + HDT * P12;
        float M02 = P02 + DT * P12 + HDT * P22;
        float M11 = P11 + DT * P12;
        float M12 = P12 + DT * P22;
        float M22 = P22;
        P00 = M00 + DT * M01 + HDT * M02 + Q00;
        P01 = M01 + DT * M02 + Q01;
        P02 = M02 + Q02;
        P11 = M11 + DT * M12 + Q11;
        P12 = M12 + Q12;
        P22 = M22 + Q22;
    };
    auto kupdate = [&](float z) {
        float y = z - X0;
        float Sinv = 1.0f / (P00 + Rch);
        float K0 = P00 * Sinv, K1 = P01 * Sinv, K2 = P02 * Sinv;
        X0 += y * K0; X1 += y * K1; X2 += y * K2;
        float p00 = P00, p01 = P01, p02 = P02;
        P00 = p00 - K0 * p00;
        P01 = p01 - K0 * p01;
        P02 = p02 - K0 * p02;
        P11 = P11 - K1 * p01;
        P12 = P12 - K1 * p02;
        P22 = P22 - K2 * p02;
    };

    // one full step: XP -> Win -> 3 LSTM layers; everything wave-local
    auto stack = [&]() {
        if (q < 2) {
            unsigned short* row = &xp[m][0];
            int o = ch * 3;
            row[o + 0] = f2bf(X0); row[o + 1] = f2bf(X1); row[o + 2] = f2bf(X2);
            int pb = 6 + ch * 9;
            row[pb + 0] = f2bf(P00); row[pb + 1] = f2bf(P01); row[pb + 2] = f2bf(P02);
            row[pb + 3] = f2bf(P01); row[pb + 4] = f2bf(P11); row[pb + 5] = f2bf(P12);
            row[pb + 6] = f2bf(P02); row[pb + 7] = f2bf(P12); row[pb + 8] = f2bf(P22);
        }
        __builtin_amdgcn_wave_barrier();
        bfrag8 bxp = *(const bfrag8*)&xp[m][q * 8];
        __builtin_amdgcn_wave_barrier();
        // Win -> x0 directly in B-frag layout
        f32x4 t0 = __builtin_amdgcn_mfma_f32_16x16x32_bf16(winF0, bxp, winC0, 0, 0, 0);
        f32x4 t1 = __builtin_amdgcn_mfma_f32_16x16x32_bf16(winF1, bxp, winC1, 0, 0, 0);
        union { unsigned int u[4]; bfrag8 v; } xu;
        xu.u[0] = pack2bf(th_(t0[0]), th_(t0[1]));
        xu.u[1] = pack2bf(th_(t0[2]), th_(t0[3]));
        xu.u[2] = pack2bf(th_(t1[0]), th_(t1[1]));
        xu.u[3] = pack2bf(th_(t1[2]), th_(t1[3]));
        xfrag = xu.v;
#pragma unroll
        for (int l = 0; l < 3; ++l) {
            f32x4 acc[8];
#pragma unroll
            for (int j = 0; j < 8; ++j) {
                f32x4 hh = __builtin_amdgcn_mfma_f32_16x16x32_bf16(fragA[l][j][1], hfrag[l], biasC[l][j], 0, 0, 0);
                acc[j]   = __builtin_amdgcn_mfma_f32_16x16x32_bf16(fragA[l][j][0], xfrag, hh, 0, 0, 0);
            }
            union { unsigned int u[4]; bfrag8 v; } xu2, hu2;
#pragma unroll
            for (int jp = 0; jp < 4; ++jp) {
                float cn[2], hn[2];
#pragma unroll
                for (int e = 0; e < 2; ++e) {
                    int j = jp * 2 + e;
                    float iv = rcp1(acc[j][0]);
                    float fv = rcp1(acc[j][1]);
                    float gv = th_(acc[j][2]);
                    float ov = rcp1(acc[j][3]);
                    float cv = fmaf(fv, cst[l][j], iv * gv);
                    cst[l][j] = cv;
                    float tc = th_(cv * TWOLOG2E);
                    cn[e] = cv; hn[e] = ov * tc;
                }
                xu2.u[jp] = pack2bf(cn[0], cn[1]);
                hu2.u[jp] = pack2bf(hn[0], hn[1]);
            }
            xfrag = xu2.v;     // = c_l, B-frag for layer l+1 (or Wout)
            hfrag[l] = hu2.v;  // B-frag for next timestep's hh MFMA
        }
    };

    const f32x4 zero4 = {0.f, 0.f, 0.f, 0.f};

    // ---------------- encoder: 19 steps ----------------
    float znext = (q < 2) ? hist[b_elem * 40 + 2 + ch] : 0.f;
#pragma unroll 1
    for (int t = 0; t < T_HIST - 1; ++t) {
        stack();
        float z = znext;
        if (t < 18) znext = (q < 2) ? hist[b_elem * 40 + (t + 2) * 2 + ch] : 0.f;
        kpred(ge0 * ge0, ge0 * ge1, ge0 * ge2, ge1 * ge1, ge1 * ge2, ge2 * ge2);
        kupdate(z);
    }

    load_phase(1);

    // ---------------- decoder: 30 steps ----------------
#pragma unroll 1
    for (int t = 0; t < LEN_PRED; ++t) {
        stack();
        f32x4 ap = __builtin_amdgcn_mfma_f32_16x16x32_bf16(woutF, xfrag, zero4, 0, 0, 0);
        float s0 = __shfl(ap[0] + wb0, m);      // preds live on q==0 lanes; broadcast by elem
        float s1 = __shfl(ap[1] + wb1, m);
        float s2 = __shfl(ap[2] + wb2, m);
        float s3 = __shfl(ap[3] + wb3, m);
        float pe = ch ? s1 : s0;
        float qe = ch ? s3 : s2;
        X2 = DT * pe;
        float qs = qe * qe;
        kpred(qs * g0 * g0, qs * g0 * g1, qs * g0 * g2, qs * g1 * g1, qs * g1 * g2, qs * g2 * g2);
        if (q < 2) {
            float* o = out + (size_t)b_elem * (LEN_PRED * 5) + t * 5;
            if (ch == 0) { o[0] = X0; o[2] = sqrtf(P00); }
            else         { o[1] = X0; o[3] = sqrtf(P00); o[4] = 0.f; }
        }
    }
}

extern "C" void kernel_launch(void* const* d_in, const int* in_sizes, int n_in,
                              void* d_out, int out_size, void* d_ws, size_t ws_size,
                              hipStream_t stream)
{
    const float* hist  = (const float*)d_in[0];
    const float* maxax = (const float*)d_in[1];
    const float* maxay = (const float*)d_in[2];
    const float* vstd  = (const float*)d_in[3];
    const float* astd  = (const float*)d_in[4];
    const float* Rx    = (const float*)d_in[5];
    const float* Ry    = (const float*)d_in[6];
    const float* Gx    = (const float*)d_in[7];
    const float* Gy    = (const float*)d_in[8];
    const float* WinW  = (const float*)d_in[9];
    const float* Winb  = (const float*)d_in[10];
    const float* eWih  = (const float*)d_in[11];
    const float* eWhh  = (const float*)d_in[12];
    const float* ebih  = (const float*)d_in[13];
    const float* ebhh  = (const float*)d_in[14];
    const float* dWih  = (const float*)d_in[15];
    const float* dWhh  = (const float*)d_in[16];
    const float* dbih  = (const float*)d_in[17];
    const float* dbhh  = (const float*)d_in[18];
    const float* WoutW = (const float*)d_in[19];
    const float* Woutb = (const float*)d_in[20];
    char* ws = (char*)d_ws;
    float* out = (float*)d_out;

    prep_kernel<<<200, 256, 0, stream>>>(WinW, Winb, eWih, eWhh, ebih, ebhh,
                                         dWih, dWhh, dbih, dbhh, WoutW, Woutb, ws);
    kalman_lstm_kernel<<<512, 64, 0, stream>>>(hist, maxax, maxay, vstd, astd,
                                               Rx, Ry, Gx, Gy, ws, out);
}

// Round 7
// 212.080 us; speedup vs baseline: 1.2293x; 1.0238x over previous
//
#include <hip/hip_runtime.h>
#include <math.h>

#define DT   0.1f
#define HDT  0.005f
#define T_HIST 20
#define LEN_PRED 30
#define NLOG2E   (-1.4426950408889634f)
#define TWOLOG2E ( 2.8853900817779268f)

typedef __attribute__((ext_vector_type(8))) short bfrag8;   // 8 bf16 = 4 VGPRs
typedef __attribute__((ext_vector_type(4))) float f32x4;

// d_ws layout (bytes)
#define WS_FRAG  0u          // 96 frags * 512 bf16 * 2B = 98304
#define WS_WIN   98304u      // 2 frags * 1024B
#define WS_WOUT  100352u     // 1 frag * 1024B
#define WS_BIASC 101376u     // 96 f32x4 = 1536B  [(ph*3+l)*8+j][q] scaled bih+bhh
#define WS_WINC  102912u     // 8 f32x4 = 128B    [T][q] scaled Win_b
#define WS_WOUTB 103040u     // 4 floats

static __device__ __forceinline__ unsigned short f2bf(float x) {
    union { float f; unsigned int u; } v; v.f = x;
    unsigned int r = v.u + 0x7fffu + ((v.u >> 16) & 1u);   // RNE
    return (unsigned short)(r >> 16);
}

// pack two floats to bf16x2 (round-half-up): lo in low16, hi in high16
static __device__ __forceinline__ unsigned int pack2bf(float lo, float hi) {
    unsigned int ul = __float_as_uint(lo) + 0x8000u;
    unsigned int uh = __float_as_uint(hi) + 0x8000u;
    return __builtin_amdgcn_perm(uh, ul, 0x07060302u);   // {uh[31:16], ul[31:16]}
}

static __device__ __forceinline__ float rcp1(float z) {   // 1/(1+2^z)
    return __builtin_amdgcn_rcpf(1.f + __builtin_amdgcn_exp2f(z));
}
static __device__ __forceinline__ float th_(float z) {    // tanh-form, z pre-scaled 2log2e
    return fmaf(-2.f, rcp1(z), 1.f);
}

// ---------------- weight prep (identical to R6) ----------------
// Layer tile j: row p ==> W-row (p&3)*32 + 8*(p>>2) + j  => D at lane(q,m): reg r = gate r,
// feat = 8q+j, elem = m => elementwise output IS the next MFMA's B-fragment. Rows pre-scaled
// for exp2 (i/f/o: -log2e, g: 2log2e). Win tile T: row p ==> feat 8*(p>>2)+4T+(p&3).
__global__ void prep_kernel(const float* __restrict__ Win_W, const float* __restrict__ Win_b,
                            const float* __restrict__ eWih, const float* __restrict__ eWhh,
                            const float* __restrict__ ebih, const float* __restrict__ ebhh,
                            const float* __restrict__ dWih, const float* __restrict__ dWhh,
                            const float* __restrict__ dbih, const float* __restrict__ dbhh,
                            const float* __restrict__ Wout_W, const float* __restrict__ Wout_b,
                            char* __restrict__ ws)
{
    int i = blockIdx.x * blockDim.x + threadIdx.x;
    if (i < 49152) {
        int fi = i >> 9, w = i & 511;
        int lane = w >> 3, jj = w & 7;
        int c = fi & 1, j = (fi >> 1) & 7, pl = fi >> 4;
        int l = pl % 3, ph = pl / 3;
        int mm = lane & 15, qq = lane >> 4;
        int gate = mm & 3;
        int row = gate * 32 + 8 * (mm >> 2) + j;
        int k = qq * 8 + jj;
        float scale = (gate == 2) ? TWOLOG2E : NLOG2E;
        const float* W = c ? (ph ? dWhh : eWhh) : (ph ? dWih : eWih);
        ((unsigned short*)(ws + WS_FRAG))[i] = f2bf(W[l * 4096 + row * 32 + k] * scale);
    } else if (i < 50176) {
        int i2 = i - 49152;
        int T = i2 >> 9, w = i2 & 511;
        int lane = w >> 3, jj = w & 7;
        int mm = lane & 15, qq = lane >> 4;
        int feat = 8 * (mm >> 2) + 4 * T + (mm & 3);
        int k = qq * 8 + jj;
        float v = (k < 24) ? Win_W[feat * 24 + k] * TWOLOG2E : 0.f;
        ((unsigned short*)(ws + WS_WIN))[i2] = f2bf(v);
    } else if (i < 50688) {
        int i3 = i - 50176;
        int lane = i3 >> 3, jj = i3 & 7;
        int mm = lane & 15, qq = lane >> 4;
        float v = (mm < 4) ? Wout_W[mm * 32 + qq * 8 + jj] : 0.f;   // unscaled
        ((unsigned short*)(ws + WS_WOUT))[i3] = f2bf(v);
    } else if (i < 51072) {
        int b = i - 50688;                 // ((ph*3+l)*8+j)*16 + q*4 + r
        int r = b & 3, qq = (b >> 2) & 3, j = (b >> 4) & 7, pl = b >> 7;
        int l = pl % 3, ph = pl / 3;
        int row = r * 32 + 8 * qq + j;
        float scale = (r == 2) ? TWOLOG2E : NLOG2E;
        const float* bi = ph ? dbih : ebih;
        const float* bh = ph ? dbhh : ebhh;
        ((float*)(ws + WS_BIASC))[b] = (bi[l * 128 + row] + bh[l * 128 + row]) * scale;
    } else if (i < 51104) {
        int b = i - 51072;                 // T*16 + q*4 + r -> Win_b[8q+4T+r]
        int r = b & 3, qq = (b >> 2) & 3, T = b >> 4;
        ((float*)(ws + WS_WINC))[b] = Win_b[8 * qq + 4 * T + r] * TWOLOG2E;
    } else if (i < 51108) {
        ((float*)(ws + WS_WOUTB))[i - 51104] = Wout_b[i - 51104];
    }
}

// ---------------- main kernel: 1 wave / 8 elems, 1024 waves (1 per SIMD), zero barriers ----
// Elementwise stays dense: lanes m>=8 take feats 4..7 of elem m-8 via shfl_xor(8) repack.
__launch_bounds__(64)
__global__ void kalman_lstm_kernel(const float* __restrict__ hist,
                                   const float* __restrict__ max_ax, const float* __restrict__ max_ay,
                                   const float* __restrict__ vstd, const float* __restrict__ astd,
                                   const float* __restrict__ Rx_, const float* __restrict__ Ry_,
                                   const float* __restrict__ Gx, const float* __restrict__ Gy,
                                   const char* __restrict__ ws, float* __restrict__ out)
{
    __shared__ unsigned short xp[16][40];   // wave-private XP staging (rows 8..15 stay 0)

    const int lane = threadIdx.x;
    const int q = lane >> 4, m = lane & 15, ch = q & 1;
    const bool act = (m < 8);               // MFMA cols 0..7 are the real elems
    const int b_elem = blockIdx.x * 8 + (m & 7);

    for (int i = lane; i < 640; i += 64) (&xp[0][0])[i] = 0;
    __builtin_amdgcn_wave_barrier();

    // ---- full weight stack in registers (per phase) ----
    bfrag8 fragA[3][8][2];     // [layer][tile j][0=ih,1=hh]
    f32x4  biasC[3][8];        // MFMA C-operand biases
    const bfrag8* fragp = (const bfrag8*)(ws + WS_FRAG);
    const f32x4*  biasp = (const f32x4*)(ws + WS_BIASC);
    auto load_phase = [&](int ph) {
#pragma unroll
        for (int l = 0; l < 3; ++l)
#pragma unroll
            for (int j = 0; j < 8; ++j) {
#pragma unroll
                for (int c = 0; c < 2; ++c)
                    fragA[l][j][c] = fragp[(((ph * 3 + l) * 8 + j) * 2 + c) * 64 + lane];
                biasC[l][j] = biasp[((ph * 3 + l) * 8 + j) * 4 + q];
            }
    };
    load_phase(0);

    bfrag8 winF0 = ((const bfrag8*)(ws + WS_WIN))[lane];
    bfrag8 winF1 = ((const bfrag8*)(ws + WS_WIN))[64 + lane];
    f32x4  winC0 = ((const f32x4*)(ws + WS_WINC))[q];
    f32x4  winC1 = ((const f32x4*)(ws + WS_WINC))[4 + q];
    bfrag8 woutF = ((const bfrag8*)(ws + WS_WOUT))[lane];
    const float* wbp = (const float*)(ws + WS_WOUTB);
    const float wb0 = wbp[0], wb1 = wbp[1], wb2 = wbp[2], wb3 = wbp[3];

    // ---- Kalman state (q<2 && m<8 lanes authoritative; others junk-but-finite) ----
    const float rx = Rx_[0] * Rx_[0], ry = Ry_[0] * Ry_[0];
    const float Rch = ch ? ry : rx;
    float g0, g1, g2, s;
    if (ch == 0) { g0 = Gx[0]; g1 = Gx[1]; g2 = Gx[2]; s = max_ax[0]; }
    else         { g0 = Gy[0]; g1 = Gy[1]; g2 = Gy[2]; s = max_ay[0]; }
    const float ge0 = g0 * s, ge1 = g1 * s, ge2 = g2 * s;
    float X0 = (q < 2 && act) ? hist[b_elem * 40 + ch] : 0.f;
    float X1 = 0.f, X2 = 0.f;
    float P00 = Rch, P01 = 0.f, P02 = 0.f;
    float P11 = vstd[0] * vstd[0], P12 = 0.f, P22 = astd[0] * astd[0];

    // ---- LSTM state: lane (q,m) owns feats 8q + (m<8 ? 0..3 : 4..7) of elem m&7 ----
    union { unsigned int u[4]; bfrag8 v; } zf; zf.u[0] = zf.u[1] = zf.u[2] = zf.u[3] = 0;
    bfrag8 hfrag[3] = { zf.v, zf.v, zf.v };
    bfrag8 xfrag = zf.v;
    float cst[3][4];
#pragma unroll
    for (int l = 0; l < 3; ++l)
#pragma unroll
        for (int k = 0; k < 4; ++k) cst[l][k] = 0.f;

    auto kpred = [&](float Q00, float Q01, float Q02, float Q11, float Q12, float Q22) {
        X0 = X0 + DT * X1 + HDT * X2;
        X1 = X1 + DT * X2;
        float M00 = P00 + DT * P01 + HDT * P02;
        float M01 = P01 + DT * P11 + HDT * P12;
        float M02 = P02 + DT * P12 + HDT * P22;
        float M11 = P11 + DT * P12;
        float M12 = P12 + DT * P22;
        float M22 = P22;
        P00 = M00 + DT * M01 + HDT * M02 + Q00;
        P01 = M01 + DT * M02 + Q01;
        P02 = M02 + Q02;
        P11 = M11 + DT * M12 + Q11;
        P12 = M12 + Q12;
        P22 = M22 + Q22;
    };
    auto kupdate = [&](float z) {
        float y = z - X0;
        float Sinv = 1.0f / (P00 + Rch);
        float K0 = P00 * Sinv, K1 = P01 * Sinv, K2 = P02 * Sinv;
        X0 += y * K0; X1 += y * K1; X2 += y * K2;
        float p00 = P00, p01 = P01, p02 = P02;
        P00 = p00 - K0 * p00;
        P01 = p01 - K0 * p01;
        P02 = p02 - K0 * p02;
        P11 = P11 - K1 * p01;
        P12 = P12 - K1 * p02;
        P22 = P22 - K2 * p02;
    };

    // one full step: XP -> Win -> 3 LSTM layers; wave-local, no barriers
    auto stack = [&]() {
        if (q < 2 && act) {
            unsigned short* row = &xp[m][0];
            int o = ch * 3;
            row[o + 0] = f2bf(X0); row[o + 1] = f2bf(X1); row[o + 2] = f2bf(X2);
            int pb = 6 + ch * 9;
            row[pb + 0] = f2bf(P00); row[pb + 1] = f2bf(P01); row[pb + 2] = f2bf(P02);
            row[pb + 3] = f2bf(P01); row[pb + 4] = f2bf(P11); row[pb + 5] = f2bf(P12);
            row[pb + 6] = f2bf(P02); row[pb + 7] = f2bf(P12); row[pb + 8] = f2bf(P22);
        }
        __builtin_amdgcn_wave_barrier();
        bfrag8 bxp = *(const bfrag8*)&xp[m][q * 8];
        __builtin_amdgcn_wave_barrier();
        // Win -> x0 directly in B-frag layout (valid for cols m<8; rest junk-finite)
        f32x4 t0 = __builtin_amdgcn_mfma_f32_16x16x32_bf16(winF0, bxp, winC0, 0, 0, 0);
        f32x4 t1 = __builtin_amdgcn_mfma_f32_16x16x32_bf16(winF1, bxp, winC1, 0, 0, 0);
        union { unsigned int u[4]; bfrag8 v; } xu;
        xu.u[0] = pack2bf(th_(t0[0]), th_(t0[1]));
        xu.u[1] = pack2bf(th_(t0[2]), th_(t0[3]));
        xu.u[2] = pack2bf(th_(t1[0]), th_(t1[1]));
        xu.u[3] = pack2bf(th_(t1[2]), th_(t1[3]));
        xfrag = xu.v;
#pragma unroll
        for (int l = 0; l < 3; ++l) {
            f32x4 acc[8];
#pragma unroll
            for (int j = 0; j < 8; ++j) {
                f32x4 hh = __builtin_amdgcn_mfma_f32_16x16x32_bf16(fragA[l][j][1], hfrag[l], biasC[l][j], 0, 0, 0);
                acc[j]   = __builtin_amdgcn_mfma_f32_16x16x32_bf16(fragA[l][j][0], xfrag, hh, 0, 0, 0);
            }
            // dense elementwise: lanes m>=8 pull acc[k+4] from lane m-8 (elem m-8, feats 4..7)
            float cn[4], hn[4];
#pragma unroll
            for (int k = 0; k < 4; ++k) {
                float s0 = __shfl_xor(acc[k + 4][0], 8);
                float s1 = __shfl_xor(acc[k + 4][1], 8);
                float s2 = __shfl_xor(acc[k + 4][2], 8);
                float s3 = __shfl_xor(acc[k + 4][3], 8);
                float gi = act ? acc[k][0] : s0;
                float gf = act ? acc[k][1] : s1;
                float gg = act ? acc[k][2] : s2;
                float go = act ? acc[k][3] : s3;
                float iv = rcp1(gi);
                float fv = rcp1(gf);
                float gv = th_(gg);
                float ov = rcp1(go);
                float cv = fmaf(fv, cst[l][k], iv * gv);
                cst[l][k] = cv;
                cn[k] = cv;
                hn[k] = ov * th_(cv * TWOLOG2E);
            }
            // rebuild B-frags: jj 0..3 local, jj 4..7 from partner lane (m^8)
            union { unsigned int u[4]; bfrag8 v; } xv, hv;
            xv.u[0] = pack2bf(cn[0], cn[1]); xv.u[1] = pack2bf(cn[2], cn[3]);
            hv.u[0] = pack2bf(hn[0], hn[1]); hv.u[1] = pack2bf(hn[2], hn[3]);
            xv.u[2] = __shfl_xor(xv.u[0], 8); xv.u[3] = __shfl_xor(xv.u[1], 8);
            hv.u[2] = __shfl_xor(hv.u[0], 8); hv.u[3] = __shfl_xor(hv.u[1], 8);
            xfrag = xv.v;      // = c_l, B-frag for layer l+1 (or Wout)
            hfrag[l] = hv.v;   // B-frag for next timestep's hh MFMA
        }
    };

    const f32x4 zero4 = {0.f, 0.f, 0.f, 0.f};

    // ---------------- encoder: 19 steps ----------------
    float znext = (q < 2 && act) ? hist[b_elem * 40 + 2 + ch] : 0.f;
#pragma unroll 1
    for (int t = 0; t < T_HIST - 1; ++t) {
        stack();
        float z = znext;
        if (t < 18) znext = (q < 2 && act) ? hist[b_elem * 40 + (t + 2) * 2 + ch] : 0.f;
        kpred(ge0 * ge0, ge0 * ge1, ge0 * ge2, ge1 * ge1, ge1 * ge2, ge2 * ge2);
        kupdate(z);
    }

    load_phase(1);

    // ---------------- decoder: 30 steps ----------------
#pragma unroll 1
    for (int t = 0; t < LEN_PRED; ++t) {
        stack();
        f32x4 ap = __builtin_amdgcn_mfma_f32_16x16x32_bf16(woutF, xfrag, zero4, 0, 0, 0);
        float s0 = __shfl(ap[0] + wb0, m);      // preds on q==0 lanes; broadcast by elem col
        float s1 = __shfl(ap[1] + wb1, m);
        float s2 = __shfl(ap[2] + wb2, m);
        float s3 = __shfl(ap[3] + wb3, m);
        float pe = ch ? s1 : s0;
        float qe = ch ? s3 : s2;
        X2 = DT * pe;
        float qs = qe * qe;
        kpred(qs * g0 * g0, qs * g0 * g1, qs * g0 * g2, qs * g1 * g1, qs * g1 * g2, qs * g2 * g2);
        if (q < 2 && act) {
            float* o = out + (size_t)b_elem * (LEN_PRED * 5) + t * 5;
            if (ch == 0) { o[0] = X0; o[2] = sqrtf(P00); }
            else         { o[1] = X0; o[3] = sqrtf(P00); o[4] = 0.f; }
        }
    }
}

extern "C" void kernel_launch(void* const* d_in, const int* in_sizes, int n_in,
                              void* d_out, int out_size, void* d_ws, size_t ws_size,
                              hipStream_t stream)
{
    const float* hist  = (const float*)d_in[0];
    const float* maxax = (const float*)d_in[1];
    const float* maxay = (const float*)d_in[2];
    const float* vstd  = (const float*)d_in[3];
    const float* astd  = (const float*)d_in[4];
    const float* Rx    = (const float*)d_in[5];
    const float* Ry    = (const float*)d_in[6];
    const float* Gx    = (const float*)d_in[7];
    const float* Gy    = (const float*)d_in[8];
    const float* WinW  = (const float*)d_in[9];
    const float* Winb  = (const float*)d_in[10];
    const float* eWih  = (const float*)d_in[11];
    const float* eWhh  = (const float*)d_in[12];
    const float* ebih  = (const float*)d_in[13];
    const float* ebhh  = (const float*)d_in[14];
    const float* dWih  = (const float*)d_in[15];
    const float* dWhh  = (const float*)d_in[16];
    const float* dbih  = (const float*)d_in[17];
    const float* dbhh  = (const float*)d_in[18];
    const float* WoutW = (const float*)d_in[19];
    const float* Woutb = (const float*)d_in[20];
    char* ws = (char*)d_ws;
    float* out = (float*)d_out;

    prep_kernel<<<200, 256, 0, stream>>>(WinW, Winb, eWih, eWhh, ebih, ebhh,
                                         dWih, dWhh, dbih, dbhh, WoutW, Woutb, ws);
    kalman_lstm_kernel<<<1024, 64, 0, stream>>>(hist, maxax, maxay, vstd, astd,
                                                Rx, Ry, Gx, Gy, ws, out);
}

// Round 8
// 200.956 us; speedup vs baseline: 1.2974x; 1.0554x over previous
//
#include <hip/hip_runtime.h>
#include <math.h>

#define DT   0.1f
#define HDT  0.005f
#define T_HIST 20
#define LEN_PRED 30
#define NLOG2E   (-1.4426950408889634f)
#define TWOLOG2E ( 2.8853900817779268f)
#define ECLAMP   40.0f

typedef __attribute__((ext_vector_type(8))) short bfrag8;   // 8 bf16 = 4 VGPRs
typedef __attribute__((ext_vector_type(4))) float f32x4;

// d_ws layout (bytes)
#define WS_FRAG  0u          // 96 frags * 512 bf16 * 2B = 98304
#define WS_WIN   98304u      // 2 frags * 1024B
#define WS_WOUT  100352u     // 1 frag * 1024B
#define WS_BIASC 101376u     // 96 f32x4 = 1536B  [(ph*3+l)*8+j][q] scaled bih+bhh
#define WS_WINC  102912u     // 8 f32x4 = 128B    [T][q] scaled Win_b
#define WS_WOUTB 103040u     // 4 floats

static __device__ __forceinline__ unsigned short f2bf(float x) {
    union { float f; unsigned int u; } v; v.f = x;
    unsigned int r = v.u + 0x7fffu + ((v.u >> 16) & 1u);   // RNE
    return (unsigned short)(r >> 16);
}

// pack two floats to bf16x2 (round-half-up): lo in low16, hi in high16
static __device__ __forceinline__ unsigned int pack2bf(float lo, float hi) {
    unsigned int ul = __float_as_uint(lo) + 0x8000u;
    unsigned int uh = __float_as_uint(hi) + 0x8000u;
    return __builtin_amdgcn_perm(uh, ul, 0x07060302u);   // {uh[31:16], ul[31:16]}
}

// lane^8 swap within each 16-lane row: DPP row_ror:8 — pure VALU, no LDS crossbar
static __device__ __forceinline__ unsigned int dpp8i(unsigned int x) {
    return (unsigned int)__builtin_amdgcn_update_dpp(0, (int)x, 0x128, 0xf, 0xf, true);
}
static __device__ __forceinline__ float dpp8f(float x) {
    return __int_as_float(__builtin_amdgcn_update_dpp(0, __float_as_int(x), 0x128, 0xf, 0xf, true));
}

static __device__ __forceinline__ float exp2c(float z) {   // clamped exp2: result <= 2^40
    return __builtin_amdgcn_exp2f(fminf(z, ECLAMP));
}
static __device__ __forceinline__ float rcp1(float z) {    // 1/(1+2^z)
    return __builtin_amdgcn_rcpf(1.f + __builtin_amdgcn_exp2f(z));
}
static __device__ __forceinline__ float th_(float z) {     // tanh-form, z pre-scaled 2log2e
    return fmaf(-2.f, rcp1(z), 1.f);
}

// ---------------- weight prep (identical to R6/R7) ----------------
// Layer tile j: row p ==> W-row (p&3)*32 + 8*(p>>2) + j  => D at lane(q,m): reg r = gate r,
// feat = 8q+j, elem = m => elementwise output IS the next MFMA's B-fragment. Rows pre-scaled
// for exp2 (i/f/o: -log2e, g: 2log2e). Win tile T: row p ==> feat 8*(p>>2)+4T+(p&3).
__global__ void prep_kernel(const float* __restrict__ Win_W, const float* __restrict__ Win_b,
                            const float* __restrict__ eWih, const float* __restrict__ eWhh,
                            const float* __restrict__ ebih, const float* __restrict__ ebhh,
                            const float* __restrict__ dWih, const float* __restrict__ dWhh,
                            const float* __restrict__ dbih, const float* __restrict__ dbhh,
                            const float* __restrict__ Wout_W, const float* __restrict__ Wout_b,
                            char* __restrict__ ws)
{
    int i = blockIdx.x * blockDim.x + threadIdx.x;
    if (i < 49152) {
        int fi = i >> 9, w = i & 511;
        int lane = w >> 3, jj = w & 7;
        int c = fi & 1, j = (fi >> 1) & 7, pl = fi >> 4;
        int l = pl % 3, ph = pl / 3;
        int mm = lane & 15, qq = lane >> 4;
        int gate = mm & 3;
        int row = gate * 32 + 8 * (mm >> 2) + j;
        int k = qq * 8 + jj;
        float scale = (gate == 2) ? TWOLOG2E : NLOG2E;
        const float* W = c ? (ph ? dWhh : eWhh) : (ph ? dWih : eWih);
        ((unsigned short*)(ws + WS_FRAG))[i] = f2bf(W[l * 4096 + row * 32 + k] * scale);
    } else if (i < 50176) {
        int i2 = i - 49152;
        int T = i2 >> 9, w = i2 & 511;
        int lane = w >> 3, jj = w & 7;
        int mm = lane & 15, qq = lane >> 4;
        int feat = 8 * (mm >> 2) + 4 * T + (mm & 3);
        int k = qq * 8 + jj;
        float v = (k < 24) ? Win_W[feat * 24 + k] * TWOLOG2E : 0.f;
        ((unsigned short*)(ws + WS_WIN))[i2] = f2bf(v);
    } else if (i < 50688) {
        int i3 = i - 50176;
        int lane = i3 >> 3, jj = i3 & 7;
        int mm = lane & 15, qq = lane >> 4;
        float v = (mm < 4) ? Wout_W[mm * 32 + qq * 8 + jj] : 0.f;   // unscaled
        ((unsigned short*)(ws + WS_WOUT))[i3] = f2bf(v);
    } else if (i < 51072) {
        int b = i - 50688;                 // ((ph*3+l)*8+j)*16 + q*4 + r
        int r = b & 3, qq = (b >> 2) & 3, j = (b >> 4) & 7, pl = b >> 7;
        int l = pl % 3, ph = pl / 3;
        int row = r * 32 + 8 * qq + j;
        float scale = (r == 2) ? TWOLOG2E : NLOG2E;
        const float* bi = ph ? dbih : ebih;
        const float* bh = ph ? dbhh : ebhh;
        ((float*)(ws + WS_BIASC))[b] = (bi[l * 128 + row] + bh[l * 128 + row]) * scale;
    } else if (i < 51104) {
        int b = i - 51072;                 // T*16 + q*4 + r -> Win_b[8q+4T+r]
        int r = b & 3, qq = (b >> 2) & 3, T = b >> 4;
        ((float*)(ws + WS_WINC))[b] = Win_b[8 * qq + 4 * T + r] * TWOLOG2E;
    } else if (i < 51108) {
        ((float*)(ws + WS_WOUTB))[i - 51104] = Wout_b[i - 51104];
    }
}

// ---------------- main kernel: 1 wave / 8 elems, 1024 waves (1 per SIMD), zero barriers ----
// Dense elementwise via DPP lane^8 repack; fused-rcp LSTM algebra (5 exp + 2 rcp / c-update).
__launch_bounds__(64)
__global__ void kalman_lstm_kernel(const float* __restrict__ hist,
                                   const float* __restrict__ max_ax, const float* __restrict__ max_ay,
                                   const float* __restrict__ vstd, const float* __restrict__ astd,
                                   const float* __restrict__ Rx_, const float* __restrict__ Ry_,
                                   const float* __restrict__ Gx, const float* __restrict__ Gy,
                                   const char* __restrict__ ws, float* __restrict__ out)
{
    __shared__ unsigned short xp[16][40];   // wave-private XP staging (rows 8..15 stay 0)

    const int lane = threadIdx.x;
    const int q = lane >> 4, m = lane & 15, ch = q & 1;
    const bool act = (m < 8);               // MFMA cols 0..7 are the real elems
    const int b_elem = blockIdx.x * 8 + (m & 7);

    for (int i = lane; i < 640; i += 64) (&xp[0][0])[i] = 0;
    __builtin_amdgcn_wave_barrier();

    // ---- full weight stack in registers (per phase) ----
    bfrag8 fragA[3][8][2];     // [layer][tile j][0=ih,1=hh]
    f32x4  biasC[3][8];        // MFMA C-operand biases
    const bfrag8* fragp = (const bfrag8*)(ws + WS_FRAG);
    const f32x4*  biasp = (const f32x4*)(ws + WS_BIASC);
    auto load_phase = [&](int ph) {
#pragma unroll
        for (int l = 0; l < 3; ++l)
#pragma unroll
            for (int j = 0; j < 8; ++j) {
#pragma unroll
                for (int c = 0; c < 2; ++c)
                    fragA[l][j][c] = fragp[(((ph * 3 + l) * 8 + j) * 2 + c) * 64 + lane];
                biasC[l][j] = biasp[((ph * 3 + l) * 8 + j) * 4 + q];
            }
    };
    load_phase(0);

    bfrag8 winF0 = ((const bfrag8*)(ws + WS_WIN))[lane];
    bfrag8 winF1 = ((const bfrag8*)(ws + WS_WIN))[64 + lane];
    f32x4  winC0 = ((const f32x4*)(ws + WS_WINC))[q];
    f32x4  winC1 = ((const f32x4*)(ws + WS_WINC))[4 + q];
    bfrag8 woutF = ((const bfrag8*)(ws + WS_WOUT))[lane];
    const float* wbp = (const float*)(ws + WS_WOUTB);
    const float wb0 = wbp[0], wb1 = wbp[1], wb2 = wbp[2], wb3 = wbp[3];

    // ---- Kalman state (q<2 && m<8 lanes authoritative; others junk-but-finite) ----
    const float rx = Rx_[0] * Rx_[0], ry = Ry_[0] * Ry_[0];
    const float Rch = ch ? ry : rx;
    float g0, g1, g2, s;
    if (ch == 0) { g0 = Gx[0]; g1 = Gx[1]; g2 = Gx[2]; s = max_ax[0]; }
    else         { g0 = Gy[0]; g1 = Gy[1]; g2 = Gy[2]; s = max_ay[0]; }
    const float ge0 = g0 * s, ge1 = g1 * s, ge2 = g2 * s;
    float X0 = (q < 2 && act) ? hist[b_elem * 40 + ch] : 0.f;
    float X1 = 0.f, X2 = 0.f;
    float P00 = Rch, P01 = 0.f, P02 = 0.f;
    float P11 = vstd[0] * vstd[0], P12 = 0.f, P22 = astd[0] * astd[0];

    // ---- LSTM state: lane (q,m) owns feats 8q + (m<8 ? 0..3 : 4..7) of elem m&7 ----
    union { unsigned int u[4]; bfrag8 v; } zf; zf.u[0] = zf.u[1] = zf.u[2] = zf.u[3] = 0;
    bfrag8 hfrag[3] = { zf.v, zf.v, zf.v };
    bfrag8 xfrag = zf.v;
    float cst[3][4];
#pragma unroll
    for (int l = 0; l < 3; ++l)
#pragma unroll
        for (int k = 0; k < 4; ++k) cst[l][k] = 0.f;

    auto kpred = [&](float Q00, float Q01, float Q02, float Q11, float Q12, float Q22) {
        X0 = X0 + DT * X1 + HDT * X2;
        X1 = X1 + DT * X2;
        float M00 = P00 + DT * P01 + HDT * P02;
        float M01 = P01 + DT * P11 + HDT * P12;
        float M02 = P02 + DT * P12 + HDT * P22;
        float M11 = P11 + DT * P12;
        float M12 = P12 + DT * P22;
        float M22 = P22;
        P00 = M00 + DT * M01 + HDT * M02 + Q00;
        P01 = M01 + DT * M02 + Q01;
        P02 = M02 + Q02;
        P11 = M11 + DT * M12 + Q11;
        P12 = M12 + Q12;
        P22 = M22 + Q22;
    };
    auto kupdate = [&](float z) {
        float y = z - X0;
        float Sinv = 1.0f / (P00 + Rch);
        float K0 = P00 * Sinv, K1 = P01 * Sinv, K2 = P02 * Sinv;
        X0 += y * K0; X1 += y * K1; X2 += y * K2;
        float p00 = P00, p01 = P01, p02 = P02;
        P00 = p00 - K0 * p00;
        P01 = p01 - K0 * p01;
        P02 = p02 - K0 * p02;
        P11 = P11 - K1 * p01;
        P12 = P12 - K1 * p02;
        P22 = P22 - K2 * p02;
    };

    // one full step: XP -> Win -> 3 LSTM layers; wave-local, no barriers
    auto stack = [&]() {
        if (q < 2 && act) {
            unsigned short* row = &xp[m][0];
            int o = ch * 3;
            row[o + 0] = f2bf(X0); row[o + 1] = f2bf(X1); row[o + 2] = f2bf(X2);
            int pb = 6 + ch * 9;
            row[pb + 0] = f2bf(P00); row[pb + 1] = f2bf(P01); row[pb + 2] = f2bf(P02);
            row[pb + 3] = f2bf(P01); row[pb + 4] = f2bf(P11); row[pb + 5] = f2bf(P12);
            row[pb + 6] = f2bf(P02); row[pb + 7] = f2bf(P12); row[pb + 8] = f2bf(P22);
        }
        __builtin_amdgcn_wave_barrier();
        bfrag8 bxp = *(const bfrag8*)&xp[m][q * 8];
        __builtin_amdgcn_wave_barrier();
        // Win -> x0 in B-frag layout; dense: lanes m>=8 tanh the partner's t1 regs
        f32x4 t0 = __builtin_amdgcn_mfma_f32_16x16x32_bf16(winF0, bxp, winC0, 0, 0, 0);
        f32x4 t1 = __builtin_amdgcn_mfma_f32_16x16x32_bf16(winF1, bxp, winC1, 0, 0, 0);
        float wv[4];
#pragma unroll
        for (int r = 0; r < 4; ++r) {
            float sp = dpp8f(t1[r]);
            wv[r] = th_(act ? t0[r] : sp);
        }
        {
            unsigned int pk0 = pack2bf(wv[0], wv[1]), pk1 = pack2bf(wv[2], wv[3]);
            unsigned int r0 = dpp8i(pk0), r1 = dpp8i(pk1);
            union { unsigned int u[4]; bfrag8 v; } xu;
            xu.u[0] = act ? pk0 : r0;
            xu.u[1] = act ? pk1 : r1;
            xu.u[2] = act ? r0 : pk0;
            xu.u[3] = act ? r1 : pk1;
            xfrag = xu.v;
        }
#pragma unroll
        for (int l = 0; l < 3; ++l) {
            f32x4 acc[8];
#pragma unroll
            for (int j = 0; j < 8; ++j) {
                f32x4 hh = __builtin_amdgcn_mfma_f32_16x16x32_bf16(fragA[l][j][1], hfrag[l], biasC[l][j], 0, 0, 0);
                acc[j]   = __builtin_amdgcn_mfma_f32_16x16x32_bf16(fragA[l][j][0], xfrag, hh, 0, 0, 0);
            }
            // dense elementwise; fused-rcp algebra: c = [c(1+I)(G+1)+(G-1)(1+F)] / [(1+F)(1+I)(G+1)]
            float cn[4], hn[4];
#pragma unroll
            for (int k = 0; k < 4; ++k) {
                float s0 = dpp8f(acc[k + 4][0]);
                float s1 = dpp8f(acc[k + 4][1]);
                float s2 = dpp8f(acc[k + 4][2]);
                float s3 = dpp8f(acc[k + 4][3]);
                float gi = act ? acc[k][0] : s0;
                float gf = act ? acc[k][1] : s1;
                float gg = act ? acc[k][2] : s2;
                float go = act ? acc[k][3] : s3;
                float I = exp2c(gi), F = exp2c(gf), G = exp2c(gg), O = exp2c(go);
                float a  = 1.f + I, b = 1.f + F;
                float gp = G + 1.f, gm = G - 1.f;
                float D1  = a * gp;
                float num = fmaf(cst[l][k], D1, gm * b);
                float den = b * D1;
                float cv  = num * __builtin_amdgcn_rcpf(den);
                cst[l][k] = cv;
                cn[k] = cv;
                float Ec = exp2c(cv * TWOLOG2E);
                float em = Ec - 1.f, ep = Ec + 1.f, o1 = 1.f + O;
                hn[k] = em * __builtin_amdgcn_rcpf(o1 * ep);
            }
            // rebuild B-frags: jj 0..3 local pack, jj 4..7 from partner lane via DPP
            union { unsigned int u[4]; bfrag8 v; } xv, hv;
            xv.u[0] = pack2bf(cn[0], cn[1]); xv.u[1] = pack2bf(cn[2], cn[3]);
            hv.u[0] = pack2bf(hn[0], hn[1]); hv.u[1] = pack2bf(hn[2], hn[3]);
            xv.u[2] = dpp8i(xv.u[0]); xv.u[3] = dpp8i(xv.u[1]);
            hv.u[2] = dpp8i(hv.u[0]); hv.u[3] = dpp8i(hv.u[1]);
            xfrag = xv.v;      // = c_l, B-frag for layer l+1 (or Wout)
            hfrag[l] = hv.v;   // B-frag for next timestep's hh MFMA
        }
    };

    const f32x4 zero4 = {0.f, 0.f, 0.f, 0.f};

    // ---------------- encoder: 19 steps ----------------
    float znext = (q < 2 && act) ? hist[b_elem * 40 + 2 + ch] : 0.f;
#pragma unroll 1
    for (int t = 0; t < T_HIST - 1; ++t) {
        stack();
        float z = znext;
        if (t < 18) znext = (q < 2 && act) ? hist[b_elem * 40 + (t + 2) * 2 + ch] : 0.f;
        kpred(ge0 * ge0, ge0 * ge1, ge0 * ge2, ge1 * ge1, ge1 * ge2, ge2 * ge2);
        kupdate(z);
    }

    load_phase(1);

    // ---------------- decoder: 30 steps ----------------
#pragma unroll 1
    for (int t = 0; t < LEN_PRED; ++t) {
        stack();
        f32x4 ap = __builtin_amdgcn_mfma_f32_16x16x32_bf16(woutF, xfrag, zero4, 0, 0, 0);
        float s0 = __shfl(ap[0] + wb0, m);      // preds on q==0 lanes; broadcast by elem col
        float s1 = __shfl(ap[1] + wb1, m);
        float s2 = __shfl(ap[2] + wb2, m);
        float s3 = __shfl(ap[3] + wb3, m);
        float pe = ch ? s1 : s0;
        float qe = ch ? s3 : s2;
        X2 = DT * pe;
        float qs = qe * qe;
        kpred(qs * g0 * g0, qs * g0 * g1, qs * g0 * g2, qs * g1 * g1, qs * g1 * g2, qs * g2 * g2);
        if (q < 2 && act) {
            float* o = out + (size_t)b_elem * (LEN_PRED * 5) + t * 5;
            if (ch == 0) { o[0] = X0; o[2] = sqrtf(P00); }
            else         { o[1] = X0; o[3] = sqrtf(P00); o[4] = 0.f; }
        }
    }
}

extern "C" void kernel_launch(void* const* d_in, const int* in_sizes, int n_in,
                              void* d_out, int out_size, void* d_ws, size_t ws_size,
                              hipStream_t stream)
{
    const float* hist  = (const float*)d_in[0];
    const float* maxax = (const float*)d_in[1];
    const float* maxay = (const float*)d_in[2];
    const float* vstd  = (const float*)d_in[3];
    const float* astd  = (const float*)d_in[4];
    const float* Rx    = (const float*)d_in[5];
    const float* Ry    = (const float*)d_in[6];
    const float* Gx    = (const float*)d_in[7];
    const float* Gy    = (const float*)d_in[8];
    const float* WinW  = (const float*)d_in[9];
    const float* Winb  = (const float*)d_in[10];
    const float* eWih  = (const float*)d_in[11];
    const float* eWhh  = (const float*)d_in[12];
    const float* ebih  = (const float*)d_in[13];
    const float* ebhh  = (const float*)d_in[14];
    const float* dWih  = (const float*)d_in[15];
    const float* dWhh  = (const float*)d_in[16];
    const float* dbih  = (const float*)d_in[17];
    const float* dbhh  = (const float*)d_in[18];
    const float* WoutW = (const float*)d_in[19];
    const float* Woutb = (const float*)d_in[20];
    char* ws = (char*)d_ws;
    float* out = (float*)d_out;

    prep_kernel<<<200, 256, 0, stream>>>(WinW, Winb, eWih, eWhh, ebih, ebhh,
                                         dWih, dWhh, dbih, dbhh, WoutW, Woutb, ws);
    kalman_lstm_kernel<<<1024, 64, 0, stream>>>(hist, maxax, maxay, vstd, astd,
                                                Rx, Ry, Gx, Gy, ws, out);
}